// Round 9
// baseline (215.895 us; speedup 1.0000x reference)
//
#include <hip/hip_runtime.h>
#include <cstdint>
#include <cstddef>

// ---------------------------------------------------------------------------
// DeMash = complex GEMM: out[bts, m] = sum_l y[bts, l] * conj(C)[m, l]
//   out_r = Yr@Cr^T + Yi@Ci^T ; out_i = Yi@Cr^T - Yr@Ci^T
// One real NT GEMM:
//   A [M=2048, K=3072] row-major fp16  (K: [Yr(1512) | Yi(1512) | 0-pad])
//   W [N=3072, K=3072] row-major fp16  (n<1512: [Cr|Ci|0]; 1512..3023:
//                                       [-Ci|Cr|0]; rest 0)
//   Out[m, n] = sum_k A[m,k] * W[n,k] -> scattered into [2,2048,14,128]
//
// R9: R3/R5/R6/R8 pin the 2-barrier K-loop at 57-59us with <=3 blocks/CU
// (OccupancyPercent ~25, all waves drain the same vmcnt(0)+barrier).
// Split-K=2: grid 1536 = 6 blocks/CU (VGPR 64 and 24KB LDS both allow it),
// 24 iters/block, epilogue unsafeAtomicAdd (native global_atomic_add_f32,
// 2-way contention) into a fully pre-zeroed out grid. Same total barrier
// count, 2x independent waves to overlap the drains.
// ---------------------------------------------------------------------------

typedef _Float16 half_t;
typedef half_t half8 __attribute__((ext_vector_type(8)));
typedef half_t half4 __attribute__((ext_vector_type(4)));
typedef half_t half2_t __attribute__((ext_vector_type(2)));
typedef float floatx4 __attribute__((ext_vector_type(4)));
typedef float floatv4 __attribute__((ext_vector_type(4)));

#define M_DIM 2048
#define N_DIM 3072
#define K_DIM 3072
#define LDIM 1512
#define NSC 108
#define SYMS 14
#define FFT 128
#define ROWLEN (SYMS * FFT)   // 1792

#define BM 64
#define BN 128
#define BK 64
#define KSPLIT 2
#define NITER_S (K_DIM / BK / KSPLIT)   // 24 iters per block

// prep grid partition (blocks of 256 threads)
#define PA2_BLOCKS 6048   // A: 2048 rows x 14 syms x 54 j-pairs / 256
#define PW2_BLOCKS 9072   // W: 3072 rows x 756 k-quads / 256
#define PAP_BLOCKS 48     // A k-pad zero: 2048 x 48 halves / 8 / 256
#define PZ_BLOCKS 7168    // FULL out zero: 2*2048*14*128 floats /4 /256
#define PREP_BLOCKS (PA2_BLOCKS + PW2_BLOCKS + PAP_BLOCKS + PZ_BLOCKS)

typedef __attribute__((address_space(3))) uint32_t lds_u32_t;
typedef const __attribute__((address_space(1))) uint32_t glob_u32_t;

__device__ __forceinline__ void gl2lds16(const void* g, void* l) {
    __builtin_amdgcn_global_load_lds((glob_u32_t*)g, (lds_u32_t*)l, 16, 0, 0);
}

// ---------------------------------------------------------------------------
// prep_all (one dispatch, 4 regions, wave-uniform region branch):
//  [0, PA2): A-build, coalesced (lanes walk subcarrier pairs).
//  [PA2, +PW2): W-build, float4 loads contiguous across lanes.
//  then A k-pad zeros, then FULL output zero (atomic epilogue needs 0 base).
// ---------------------------------------------------------------------------
__global__ __launch_bounds__(256) void prep_all(
    const float* __restrict__ xr, const float* __restrict__ xi,
    const float* __restrict__ Cr, const float* __restrict__ Ci,
    const int* __restrict__ sc,
    half_t* __restrict__ A, half_t* __restrict__ W, float* __restrict__ out)
{
    const int b = blockIdx.x;
    const int t = threadIdx.x;

    if (b < PA2_BLOCKS) {
        int idx = b * 256 + t;          // [0, 2048*14*54)
        int jp = idx % 54;
        int rest = idx / 54;
        int sym = rest % 14;
        int row = rest / 14;
        int s0 = sc[2 * jp];
        int s1 = sc[2 * jp + 1];
        const float* xrp = xr + (size_t)row * ROWLEN + sym * FFT;
        const float* xip = xi + (size_t)row * ROWLEN + sym * FFT;
        half2_t hr = { (half_t)xrp[s0], (half_t)xrp[s1] };
        half2_t hi = { (half_t)xip[s0], (half_t)xip[s1] };
        size_t dst = (size_t)row * K_DIM + sym * NSC + 2 * jp;
        *(half2_t*)(A + dst) = hr;
        *(half2_t*)(A + dst + LDIM) = hi;
    } else if (b < PA2_BLOCKS + PW2_BLOCKS) {
        int idx = (b - PA2_BLOCKS) * 256 + t;   // [0, 3072*756)
        int kq = idx % 756;
        int n = idx / 756;
        int k0 = kq * 4;
        floatv4 f = {0.0f, 0.0f, 0.0f, 0.0f};
        if (n < LDIM) {
            if (k0 < LDIM)
                f = *(const floatv4*)(Cr + (size_t)n * LDIM + k0);
            else
                f = *(const floatv4*)(Ci + (size_t)n * LDIM + (k0 - LDIM));
        } else if (n < 2 * LDIM) {
            int m = n - LDIM;
            if (k0 < LDIM) {
                f = *(const floatv4*)(Ci + (size_t)m * LDIM + k0);
                f = -f;
            } else {
                f = *(const floatv4*)(Cr + (size_t)m * LDIM + (k0 - LDIM));
            }
        }
        half4 h = { (half_t)f.x, (half_t)f.y, (half_t)f.z, (half_t)f.w };
        *(half4*)(W + (size_t)n * K_DIM + k0) = h;
    } else if (b < PA2_BLOCKS + PW2_BLOCKS + PAP_BLOCKS) {
        int idx = (b - PA2_BLOCKS - PW2_BLOCKS) * 256 + t;  // [0, 12288)
        int c = idx % 6;
        int row = idx / 6;
        half8 z = {};
        *(half8*)(A + (size_t)row * K_DIM + 2 * LDIM + c * 8) = z;
    } else {
        // zero the FULL output grid, float4 per thread
        int idx = (b - PA2_BLOCKS - PW2_BLOCKS - PAP_BLOCKS) * 256 + t;
        floatv4 z = {0.0f, 0.0f, 0.0f, 0.0f};
        *(floatv4*)(out + (size_t)idx * 4) = z;
    }
}

// ---------------------------------------------------------------------------
// gemm_scatter: 64x128 tile, BK=64, single-buffered (24 KB), 4 waves each
// 64Mx32N via 4x2 mfma_f32_16x16x32_f16 x 2 k-steps. Split-K=2: grid 1536
// (= 6 blocks/CU), block kz covers k in [kz*1536, (kz+1)*1536); epilogue
// atomic-adds into the pre-zeroed out grid. XOR bank swizzle (conflicts 0).
// ---------------------------------------------------------------------------
__global__ __launch_bounds__(256) void gemm_scatter(
    const half_t* __restrict__ A,   // [M_DIM][K_DIM]
    const half_t* __restrict__ W,   // [N_DIM][K_DIM]
    const int* __restrict__ sc,
    float* __restrict__ out)        // [2][2048][14][128]; pre-zeroed
{
    __shared__ __align__(16) half_t As[BM * BK];   // 8 KB
    __shared__ __align__(16) half_t Bs[BN * BK];   // 16 KB

    const int t = threadIdx.x;
    const int blk = blockIdx.x;          // [0, 1536)
    const int kz = blk >> 9 ? 0 : 0;     // placeholder (computed below)
    const int kzz = blk / 768;           // 0 or 1
    const int rest = blk - kzz * 768;
    const int bn = rest % 24;
    const int bm = rest / 24;
    const int kofs = kzz * (K_DIM / KSPLIT);   // 0 or 1536
    (void)kz;

    const int lane = t & 63;
    const int wn = (t >> 6) * 32;     // wave's N offset in tile

    floatx4 acc[4][2] = {};

    // staging: chunk c (16B): row = c>>3, slot = c&7, global k-chunk
    // g = slot ^ (row&7). LDS dest = base + c*16 (contiguous per lane).
    const half_t* gAp[2];
    const half_t* gBp[4];
    half_t* lAp[2];
    half_t* lBp[4];
#pragma unroll
    for (int r = 0; r < 2; ++r) {
        int c = r * 256 + t;
        int row = c >> 3, slot = c & 7;
        int g = slot ^ (row & 7);
        gAp[r] = A + (size_t)(bm * BM + row) * K_DIM + kofs + g * 8;
        lAp[r] = As + c * 8;
    }
#pragma unroll
    for (int r = 0; r < 4; ++r) {
        int c = r * 256 + t;
        int row = c >> 3, slot = c & 7;
        int g = slot ^ (row & 7);
        gBp[r] = W + (size_t)(bn * BN + row) * K_DIM + kofs + g * 8;
        lBp[r] = Bs + c * 8;
    }

    const int fr = lane & 15;         // fragment row (M or N within 16)
    const int cr = lane >> 4;         // k-quad index within a 32-k step
    const int slot0 = (cr) ^ (fr & 7);
    const int slot1 = (4 + cr) ^ (fr & 7);

    for (int kb = 0; kb < NITER_S; ++kb) {
        __syncthreads();
        gl2lds16(gAp[0], lAp[0]);
        gl2lds16(gAp[1], lAp[1]);
        gl2lds16(gBp[0], lBp[0]);
        gl2lds16(gBp[1], lBp[1]);
        gl2lds16(gBp[2], lBp[2]);
        gl2lds16(gBp[3], lBp[3]);
        gAp[0] += BK; gAp[1] += BK;
        gBp[0] += BK; gBp[1] += BK; gBp[2] += BK; gBp[3] += BK;
        __syncthreads();

        half8 af[2][4], bf[2][2];
#pragma unroll
        for (int i = 0; i < 4; ++i) {
            int rbase = (i * 16 + fr) * BK;
            af[0][i] = *(const half8*)&As[rbase + slot0 * 8];
            af[1][i] = *(const half8*)&As[rbase + slot1 * 8];
        }
#pragma unroll
        for (int j2 = 0; j2 < 2; ++j2) {
            int rbase = (wn + j2 * 16 + fr) * BK;
            bf[0][j2] = *(const half8*)&Bs[rbase + slot0 * 8];
            bf[1][j2] = *(const half8*)&Bs[rbase + slot1 * 8];
        }
#pragma unroll
        for (int s = 0; s < 2; ++s)
#pragma unroll
            for (int i = 0; i < 4; ++i)
#pragma unroll
                for (int j2 = 0; j2 < 2; ++j2)
                    acc[i][j2] = __builtin_amdgcn_mfma_f32_16x16x32_f16(
                        af[s][i], bf[s][j2], acc[i][j2], 0, 0, 0);
    }

    // epilogue: C/D layout col = lane&15 (N), row = (lane>>4)*4 + reg (M).
    // Split-K partial: atomic-add into pre-zeroed out.
    const int col_base = bn * BN + wn + (lane & 15);
    const int row_base = bm * BM + ((lane >> 4) * 4);
#pragma unroll
    for (int j2 = 0; j2 < 2; ++j2) {
        int n = col_base + j2 * 16;
        if (n >= 2 * LDIM) continue;           // N-pad region: discard
        int ri = (n >= LDIM) ? 1 : 0;
        int nn = n - ri * LDIM;
        int sym = nn / NSC;
        int jj = nn - sym * NSC;
        size_t colOff = (size_t)ri * (M_DIM * ROWLEN) + sym * FFT + sc[jj];
#pragma unroll
        for (int i = 0; i < 4; ++i) {
            int row0 = row_base + i * 16;
#pragma unroll
            for (int r = 0; r < 4; ++r) {
                unsafeAtomicAdd(&out[colOff + (size_t)(row0 + r) * ROWLEN],
                                acc[i][j2][r]);
            }
        }
    }
}

// ---------------------------------------------------------------------------
extern "C" void kernel_launch(void* const* d_in, const int* in_sizes, int n_in,
                              void* d_out, int out_size, void* d_ws, size_t ws_size,
                              hipStream_t stream) {
    const float* xr = (const float*)d_in[0];
    const float* xi = (const float*)d_in[1];
    const float* Cr = (const float*)d_in[2];
    const float* Ci = (const float*)d_in[3];
    const int* sc   = (const int*)d_in[4];
    float* out = (float*)d_out;

    half_t* Ah = (half_t*)d_ws;                                      // 12.58 MB
    half_t* Wh = (half_t*)((char*)d_ws + (size_t)M_DIM * K_DIM * 2); // 18.87 MB

    prep_all<<<PREP_BLOCKS, 256, 0, stream>>>(
        xr, xi, Cr, Ci, sc, Ah, Wh, out);

    gemm_scatter<<<768 * KSPLIT, 256, 0, stream>>>(Ah, Wh, sc, out);
}

// Round 10
// 190.087 us; speedup vs baseline: 1.1358x; 1.1358x over previous
//
#include <hip/hip_runtime.h>
#include <cstdint>
#include <cstddef>

// ---------------------------------------------------------------------------
// DeMash = complex GEMM: out[bts, m] = sum_l y[bts, l] * conj(C)[m, l]
//   out_r = Yr@Cr^T + Yi@Ci^T ; out_i = Yi@Cr^T - Yr@Ci^T
// One real NT GEMM:
//   A [M=2048, K=3072] row-major fp16  (K: [Yr(1512) | Yi(1512) | 0-pad])
//   W [N=3072, K=3072] row-major fp16  (n<1512: [Cr|Ci|0]; 1512..3023:
//                                       [-Ci|Cr|0]; rest 0)
//   Out[m, n] = sum_k A[m,k] * W[n,k] -> scattered into [2,2048,14,128]
//
// R10: cycle accounting shows R3/R7's 57us gemm is LDS-PIPE bound (~10.4MB
// LDS traffic/CU ~= 105K cyc of the 137K budget; MFMA needs only ~11K).
// B's LDS round-trip is pure waste (each wave reads a private 32-row B
// slice, reuse=1), while A has 4x cross-wave reuse. So: stage only A in
// LDS (8KB, XOR swizzle, 2-barrier loop unchanged); stream B fragments
// wave-direct from global (half8/lane, 16 fully-used 64B lines per instr),
// ping-pong prefetched 1 iter ahead (in flight across the MFMA block,
// drained by the next barrier's vmcnt(0)). LDS/block-iter: 72KB -> 40KB.
// R9's split-K + atomic epilogue reverted (atomics serialized, 117us).
// ---------------------------------------------------------------------------

typedef _Float16 half_t;
typedef half_t half8 __attribute__((ext_vector_type(8)));
typedef half_t half4 __attribute__((ext_vector_type(4)));
typedef half_t half2_t __attribute__((ext_vector_type(2)));
typedef float floatx4 __attribute__((ext_vector_type(4)));
typedef float floatv4 __attribute__((ext_vector_type(4)));

#define M_DIM 2048
#define N_DIM 3072
#define K_DIM 3072
#define LDIM 1512
#define NSC 108
#define SYMS 14
#define FFT 128
#define ROWLEN (SYMS * FFT)   // 1792

#define BM 64
#define BN 128
#define BK 64
#define NITER (K_DIM / BK)    // 48

// prep grid partition (blocks of 256 threads)  -- R7, proven
#define PA2_BLOCKS 6048   // A: 2048 rows x 14 syms x 54 j-pairs / 256
#define PW2_BLOCKS 9072   // W: 3072 rows x 756 k-quads / 256
#define PAP_BLOCKS 48     // A k-pad zero: 2048 x 48 halves / 8 / 256
#define PG_BLOCKS 4480    // guard zero: 2*2048*14*20 / 256
#define PREP_BLOCKS (PA2_BLOCKS + PW2_BLOCKS + PAP_BLOCKS + PG_BLOCKS)

typedef __attribute__((address_space(3))) uint32_t lds_u32_t;
typedef const __attribute__((address_space(1))) uint32_t glob_u32_t;

__device__ __forceinline__ void gl2lds16(const void* g, void* l) {
    __builtin_amdgcn_global_load_lds((glob_u32_t*)g, (lds_u32_t*)l, 16, 0, 0);
}

// ---------------------------------------------------------------------------
// prep_all (one dispatch, 4 regions, wave-uniform region branch):
//  [0, PA2): A-build, coalesced (lanes walk subcarrier pairs).
//  [PA2, +PW2): W-build, float4 loads contiguous across lanes.
//  then A k-pad zeros, then output guard-column zeros.   (R7, proven)
// ---------------------------------------------------------------------------
__global__ __launch_bounds__(256) void prep_all(
    const float* __restrict__ xr, const float* __restrict__ xi,
    const float* __restrict__ Cr, const float* __restrict__ Ci,
    const int* __restrict__ sc,
    half_t* __restrict__ A, half_t* __restrict__ W, float* __restrict__ out)
{
    const int b = blockIdx.x;
    const int t = threadIdx.x;

    if (b < PA2_BLOCKS) {
        int idx = b * 256 + t;          // [0, 2048*14*54)
        int jp = idx % 54;
        int rest = idx / 54;
        int sym = rest % 14;
        int row = rest / 14;
        int s0 = sc[2 * jp];
        int s1 = sc[2 * jp + 1];
        const float* xrp = xr + (size_t)row * ROWLEN + sym * FFT;
        const float* xip = xi + (size_t)row * ROWLEN + sym * FFT;
        half2_t hr = { (half_t)xrp[s0], (half_t)xrp[s1] };
        half2_t hi = { (half_t)xip[s0], (half_t)xip[s1] };
        size_t dst = (size_t)row * K_DIM + sym * NSC + 2 * jp;
        *(half2_t*)(A + dst) = hr;
        *(half2_t*)(A + dst + LDIM) = hi;
    } else if (b < PA2_BLOCKS + PW2_BLOCKS) {
        int idx = (b - PA2_BLOCKS) * 256 + t;   // [0, 3072*756)
        int kq = idx % 756;
        int n = idx / 756;
        int k0 = kq * 4;
        floatv4 f = {0.0f, 0.0f, 0.0f, 0.0f};
        if (n < LDIM) {
            if (k0 < LDIM)
                f = *(const floatv4*)(Cr + (size_t)n * LDIM + k0);
            else
                f = *(const floatv4*)(Ci + (size_t)n * LDIM + (k0 - LDIM));
        } else if (n < 2 * LDIM) {
            int m = n - LDIM;
            if (k0 < LDIM) {
                f = *(const floatv4*)(Ci + (size_t)m * LDIM + k0);
                f = -f;
            } else {
                f = *(const floatv4*)(Cr + (size_t)m * LDIM + (k0 - LDIM));
            }
        }
        half4 h = { (half_t)f.x, (half_t)f.y, (half_t)f.z, (half_t)f.w };
        *(half4*)(W + (size_t)n * K_DIM + k0) = h;
    } else if (b < PA2_BLOCKS + PW2_BLOCKS + PAP_BLOCKS) {
        int idx = (b - PA2_BLOCKS - PW2_BLOCKS) * 256 + t;  // [0, 12288)
        int c = idx % 6;
        int row = idx / 6;
        half8 z = {};
        *(half8*)(A + (size_t)row * K_DIM + 2 * LDIM + c * 8) = z;
    } else {
        // zero guard columns [0,10) U [118,128) for all 4096 rows x 14 syms
        int idx = (b - PA2_BLOCKS - PW2_BLOCKS - PAP_BLOCKS) * 256 + t;
        int c20 = idx % 20;
        int rest = idx / 20;
        int sym = rest % 14;
        int rowri = rest / 14;                 // [0, 4096) covers both ri
        int col = (c20 < 10) ? c20 : (NSC + c20);
        out[(size_t)rowri * ROWLEN + sym * FFT + col] = 0.0f;
    }
}

// ---------------------------------------------------------------------------
// gemm_scatter: 64x128 tile, BK=64. A staged in LDS (8KB, XOR swizzle,
// 2-barrier); B streamed wave-direct from global with 1-iter ping-pong
// prefetch. 4 waves each 64Mx32N via 4x2 mfma_f32_16x16x32_f16 x 2 k-steps.
// grid (24, 32) = 768 blocks = 3/CU (launch_bounds pins 3 waves/EU).
// ---------------------------------------------------------------------------
__global__ __launch_bounds__(256, 3) void gemm_scatter(
    const half_t* __restrict__ A,   // [M_DIM][K_DIM]
    const half_t* __restrict__ W,   // [N_DIM][K_DIM]
    const int* __restrict__ sc,
    float* __restrict__ out)        // [2][2048][14][128]; guards pre-zeroed
{
    __shared__ __align__(16) half_t As[BM * BK];   // 8 KB

    const int t = threadIdx.x;
    const int bn = blockIdx.x;
    const int bm = blockIdx.y;
    const int lane = t & 63;
    const int wn = (t >> 6) * 32;     // wave's N offset in tile

    floatx4 acc[4][2] = {};

    // A staging: chunk c (16B): row = c>>3, slot = c&7, global k-chunk
    // g = slot ^ (row&7). LDS dest = base + c*16 (contiguous per lane).
    const half_t* gAp[2];
    half_t* lAp[2];
#pragma unroll
    for (int r = 0; r < 2; ++r) {
        int c = r * 256 + t;
        int row = c >> 3, slot = c & 7;
        int g = slot ^ (row & 7);
        gAp[r] = A + (size_t)(bm * BM + row) * K_DIM + g * 8;
        lAp[r] = As + c * 8;
    }

    const int fr = lane & 15;         // fragment row (M or N within 16)
    const int cr = lane >> 4;         // k-quad index within a 32-k step
    const int slot0 = (cr) ^ (fr & 7);
    const int slot1 = (4 + cr) ^ (fr & 7);

    // B wave-direct pointers: lane reads W[bn*BN + wn + j*16 + fr]
    //                                  [kb*64 + s*32 + cr*8 .. +8]
    // lanes {fr} x {cr} cover 16 rows x 64B -> 16 fully-used lines/instr.
    const half_t* wp0 = W + (size_t)(bn * BN + wn + fr) * K_DIM + cr * 8;
    const half_t* wp1 = wp0 + (size_t)16 * K_DIM;

    half8 bf[2][2][2];   // [parity][s][j]
    bf[0][0][0] = *(const half8*)(wp0);
    bf[0][0][1] = *(const half8*)(wp1);
    bf[0][1][0] = *(const half8*)(wp0 + 32);
    bf[0][1][1] = *(const half8*)(wp1 + 32);

    for (int kb = 0; kb < NITER; ++kb) {
        const int par = kb & 1;
        __syncthreads();
        gl2lds16(gAp[0], lAp[0]);
        gl2lds16(gAp[1], lAp[1]);
        gAp[0] += BK; gAp[1] += BK;
        __syncthreads();

        // prefetch B for kb+1: in flight across this iter's MFMA block,
        // drained (worst case) by the next barrier's vmcnt(0).
        if (kb + 1 < NITER) {
            const half_t* b0 = wp0 + (kb + 1) * BK;
            const half_t* b1 = wp1 + (kb + 1) * BK;
            bf[par ^ 1][0][0] = *(const half8*)(b0);
            bf[par ^ 1][0][1] = *(const half8*)(b1);
            bf[par ^ 1][1][0] = *(const half8*)(b0 + 32);
            bf[par ^ 1][1][1] = *(const half8*)(b1 + 32);
        }

        half8 af[2][4];
#pragma unroll
        for (int i = 0; i < 4; ++i) {
            int rbase = (i * 16 + fr) * BK;
            af[0][i] = *(const half8*)&As[rbase + slot0 * 8];
            af[1][i] = *(const half8*)&As[rbase + slot1 * 8];
        }
#pragma unroll
        for (int s = 0; s < 2; ++s)
#pragma unroll
            for (int i = 0; i < 4; ++i)
#pragma unroll
                for (int j2 = 0; j2 < 2; ++j2)
                    acc[i][j2] = __builtin_amdgcn_mfma_f32_16x16x32_f16(
                        af[s][i], bf[par][s][j2], acc[i][j2], 0, 0, 0);
    }

    // epilogue: C/D layout col = lane&15 (N), row = (lane>>4)*4 + reg (M)
    const int col_base = bn * BN + wn + (lane & 15);
    const int row_base = bm * BM + ((lane >> 4) * 4);
#pragma unroll
    for (int j2 = 0; j2 < 2; ++j2) {
        int n = col_base + j2 * 16;
        if (n >= 2 * LDIM) continue;           // N-pad region: discard
        int ri = (n >= LDIM) ? 1 : 0;
        int nn = n - ri * LDIM;
        int sym = nn / NSC;
        int jj = nn - sym * NSC;
        size_t colOff = (size_t)ri * (M_DIM * ROWLEN) + sym * FFT + sc[jj];
#pragma unroll
        for (int i = 0; i < 4; ++i) {
            int row0 = row_base + i * 16;
#pragma unroll
            for (int r = 0; r < 4; ++r) {
                out[colOff + (size_t)(row0 + r) * ROWLEN] = acc[i][j2][r];
            }
        }
    }
}

// ---------------------------------------------------------------------------
extern "C" void kernel_launch(void* const* d_in, const int* in_sizes, int n_in,
                              void* d_out, int out_size, void* d_ws, size_t ws_size,
                              hipStream_t stream) {
    const float* xr = (const float*)d_in[0];
    const float* xi = (const float*)d_in[1];
    const float* Cr = (const float*)d_in[2];
    const float* Ci = (const float*)d_in[3];
    const int* sc   = (const int*)d_in[4];
    float* out = (float*)d_out;

    half_t* Ah = (half_t*)d_ws;                                      // 12.58 MB
    half_t* Wh = (half_t*)((char*)d_ws + (size_t)M_DIM * K_DIM * 2); // 18.87 MB

    prep_all<<<PREP_BLOCKS, 256, 0, stream>>>(
        xr, xi, Cr, Ci, sc, Ah, Wh, out);

    dim3 grid(N_DIM / BN, M_DIM / BM);   // (24, 32) = 768 blocks
    gemm_scatter<<<grid, 256, 0, stream>>>(Ah, Wh, sc, out);
}

// Round 11
// 153.817 us; speedup vs baseline: 1.4036x; 1.2358x over previous
//
#include <hip/hip_runtime.h>
#include <cstdint>
#include <cstddef>

// ---------------------------------------------------------------------------
// DeMash = complex GEMM: out[bts, m] = sum_l y[bts, l] * conj(C)[m, l]
//   out_r = Yr@Cr^T + Yi@Ci^T ; out_i = Yi@Cr^T - Yr@Ci^T
// One real NT GEMM:
//   A [M=2048, K=3072] row-major fp16  (K: [Yr(1512) | Yi(1512) | 0-pad])
//   W [N=3072, K=3072] row-major fp16  (n<1512: [Cr|Ci|0]; 1512..3023:
//                                       [-Ci|Cr|0]; rest 0)
//   Out[m, n] = sum_k A[m,k] * W[n,k] -> scattered into [2,2048,14,128]
//
// R11: R10's B-streaming regressed (93us) -- register B-loads share vmcnt
// with global_load_lds, so the barrier drained their full global latency
// every iter; LDS-pipe model falsified. Corrected model: the 57us R7 gemm
// is DRAIN-COUNT bound (48 exposed ~350cyc L2 drains). Only untried lever
// on drain count: BK=128 at UNCHANGED occupancy (64x128 tile -> 48KB LDS,
// still 3 blocks/CU; m132's BK=128 failure was the 2-blocks/CU occupancy
// drop at a 128^2 tile, avoided here). 24 barriers, 32 MFMA per drain.
// ---------------------------------------------------------------------------

typedef _Float16 half_t;
typedef half_t half8 __attribute__((ext_vector_type(8)));
typedef half_t half4 __attribute__((ext_vector_type(4)));
typedef half_t half2_t __attribute__((ext_vector_type(2)));
typedef float floatx4 __attribute__((ext_vector_type(4)));
typedef float floatv4 __attribute__((ext_vector_type(4)));

#define M_DIM 2048
#define N_DIM 3072
#define K_DIM 3072
#define LDIM 1512
#define NSC 108
#define SYMS 14
#define FFT 128
#define ROWLEN (SYMS * FFT)   // 1792

#define BM 64
#define BN 128
#define BK 128
#define NITER (K_DIM / BK)    // 24

// prep grid partition (blocks of 256 threads)  -- R7, proven
#define PA2_BLOCKS 6048   // A: 2048 rows x 14 syms x 54 j-pairs / 256
#define PW2_BLOCKS 9072   // W: 3072 rows x 756 k-quads / 256
#define PAP_BLOCKS 48     // A k-pad zero: 2048 x 48 halves / 8 / 256
#define PG_BLOCKS 4480    // guard zero: 2*2048*14*20 / 256
#define PREP_BLOCKS (PA2_BLOCKS + PW2_BLOCKS + PAP_BLOCKS + PG_BLOCKS)

typedef __attribute__((address_space(3))) uint32_t lds_u32_t;
typedef const __attribute__((address_space(1))) uint32_t glob_u32_t;

__device__ __forceinline__ void gl2lds16(const void* g, void* l) {
    __builtin_amdgcn_global_load_lds((glob_u32_t*)g, (lds_u32_t*)l, 16, 0, 0);
}

// ---------------------------------------------------------------------------
// prep_all (one dispatch, 4 regions, wave-uniform region branch):
//  [0, PA2): A-build, coalesced (lanes walk subcarrier pairs).
//  [PA2, +PW2): W-build, float4 loads contiguous across lanes.
//  then A k-pad zeros, then output guard-column zeros.   (R7, proven)
// ---------------------------------------------------------------------------
__global__ __launch_bounds__(256) void prep_all(
    const float* __restrict__ xr, const float* __restrict__ xi,
    const float* __restrict__ Cr, const float* __restrict__ Ci,
    const int* __restrict__ sc,
    half_t* __restrict__ A, half_t* __restrict__ W, float* __restrict__ out)
{
    const int b = blockIdx.x;
    const int t = threadIdx.x;

    if (b < PA2_BLOCKS) {
        int idx = b * 256 + t;          // [0, 2048*14*54)
        int jp = idx % 54;
        int rest = idx / 54;
        int sym = rest % 14;
        int row = rest / 14;
        int s0 = sc[2 * jp];
        int s1 = sc[2 * jp + 1];
        const float* xrp = xr + (size_t)row * ROWLEN + sym * FFT;
        const float* xip = xi + (size_t)row * ROWLEN + sym * FFT;
        half2_t hr = { (half_t)xrp[s0], (half_t)xrp[s1] };
        half2_t hi = { (half_t)xip[s0], (half_t)xip[s1] };
        size_t dst = (size_t)row * K_DIM + sym * NSC + 2 * jp;
        *(half2_t*)(A + dst) = hr;
        *(half2_t*)(A + dst + LDIM) = hi;
    } else if (b < PA2_BLOCKS + PW2_BLOCKS) {
        int idx = (b - PA2_BLOCKS) * 256 + t;   // [0, 3072*756)
        int kq = idx % 756;
        int n = idx / 756;
        int k0 = kq * 4;
        floatv4 f = {0.0f, 0.0f, 0.0f, 0.0f};
        if (n < LDIM) {
            if (k0 < LDIM)
                f = *(const floatv4*)(Cr + (size_t)n * LDIM + k0);
            else
                f = *(const floatv4*)(Ci + (size_t)n * LDIM + (k0 - LDIM));
        } else if (n < 2 * LDIM) {
            int m = n - LDIM;
            if (k0 < LDIM) {
                f = *(const floatv4*)(Ci + (size_t)m * LDIM + k0);
                f = -f;
            } else {
                f = *(const floatv4*)(Cr + (size_t)m * LDIM + (k0 - LDIM));
            }
        }
        half4 h = { (half_t)f.x, (half_t)f.y, (half_t)f.z, (half_t)f.w };
        *(half4*)(W + (size_t)n * K_DIM + k0) = h;
    } else if (b < PA2_BLOCKS + PW2_BLOCKS + PAP_BLOCKS) {
        int idx = (b - PA2_BLOCKS - PW2_BLOCKS) * 256 + t;  // [0, 12288)
        int c = idx % 6;
        int row = idx / 6;
        half8 z = {};
        *(half8*)(A + (size_t)row * K_DIM + 2 * LDIM + c * 8) = z;
    } else {
        // zero guard columns [0,10) U [118,128) for all 4096 rows x 14 syms
        int idx = (b - PA2_BLOCKS - PW2_BLOCKS - PAP_BLOCKS) * 256 + t;
        int c20 = idx % 20;
        int rest = idx / 20;
        int sym = rest % 14;
        int rowri = rest / 14;                 // [0, 4096) covers both ri
        int col = (c20 < 10) ? c20 : (NSC + c20);
        out[(size_t)rowri * ROWLEN + sym * FFT + col] = 0.0f;
    }
}

// ---------------------------------------------------------------------------
// gemm_scatter: 64x128 tile, BK=128, single-buffered (16+32=48 KB LDS,
// 3 blocks/CU). 4 waves each 64Mx32N via 4x2 mfma_f32_16x16x32_f16 x 4
// k-steps = 32 MFMA per barrier (24 barriers total, was 48). XOR bank
// swizzle on 16B chunks (slot low-3-bit XOR row&7; conflicts = 0).
// grid (24, 32) = 768 blocks.
// ---------------------------------------------------------------------------
__global__ __launch_bounds__(256, 3) void gemm_scatter(
    const half_t* __restrict__ A,   // [M_DIM][K_DIM]
    const half_t* __restrict__ W,   // [N_DIM][K_DIM]
    const int* __restrict__ sc,
    float* __restrict__ out)        // [2][2048][14][128]; guards pre-zeroed
{
    __shared__ __align__(16) half_t As[BM * BK];   // 16 KB
    __shared__ __align__(16) half_t Bs[BN * BK];   // 32 KB

    const int t = threadIdx.x;
    const int bn = blockIdx.x;
    const int bm = blockIdx.y;
    const int lane = t & 63;
    const int wn = (t >> 6) * 32;     // wave's N offset in tile

    floatx4 acc[4][2] = {};

    // staging: chunk c (16B): row = c>>4, slot = c&15, global k-chunk
    // g = slot ^ (row&7) (XOR flips only low 3 bits -> stays in [0,16)).
    // LDS dest = base + c*16 (contiguous per lane => legal gl2lds dest).
    const half_t* gAp[4];
    const half_t* gBp[8];
    half_t* lAp[4];
    half_t* lBp[8];
#pragma unroll
    for (int r = 0; r < 4; ++r) {
        int c = r * 256 + t;
        int row = c >> 4, slot = c & 15;
        int g = slot ^ (row & 7);
        gAp[r] = A + (size_t)(bm * BM + row) * K_DIM + g * 8;
        lAp[r] = As + c * 8;
    }
#pragma unroll
    for (int r = 0; r < 8; ++r) {
        int c = r * 256 + t;
        int row = c >> 4, slot = c & 15;
        int g = slot ^ (row & 7);
        gBp[r] = W + (size_t)(bn * BN + row) * K_DIM + g * 8;
        lBp[r] = Bs + c * 8;
    }

    const int fr = lane & 15;         // fragment row (M or N within 16)
    const int cr = lane >> 4;         // k-quad index within a 32-k step
    // physical slot for k-step s: (s*4 + cr) ^ (fr&7)
    int slots[4];
#pragma unroll
    for (int s = 0; s < 4; ++s) slots[s] = ((s * 4 + cr) ^ (fr & 7)) * 8;

    for (int kb = 0; kb < NITER; ++kb) {
        __syncthreads();
#pragma unroll
        for (int r = 0; r < 4; ++r) {
            gl2lds16(gAp[r], lAp[r]);
            gAp[r] += BK;
        }
#pragma unroll
        for (int r = 0; r < 8; ++r) {
            gl2lds16(gBp[r], lBp[r]);
            gBp[r] += BK;
        }
        __syncthreads();

#pragma unroll
        for (int s = 0; s < 4; ++s) {
            half8 af[4], bf[2];
#pragma unroll
            for (int i = 0; i < 4; ++i)
                af[i] = *(const half8*)&As[(i * 16 + fr) * BK + slots[s]];
#pragma unroll
            for (int j2 = 0; j2 < 2; ++j2)
                bf[j2] = *(const half8*)&Bs[(wn + j2 * 16 + fr) * BK + slots[s]];
#pragma unroll
            for (int i = 0; i < 4; ++i)
#pragma unroll
                for (int j2 = 0; j2 < 2; ++j2)
                    acc[i][j2] = __builtin_amdgcn_mfma_f32_16x16x32_f16(
                        af[i], bf[j2], acc[i][j2], 0, 0, 0);
        }
    }

    // epilogue: C/D layout col = lane&15 (N), row = (lane>>4)*4 + reg (M)
    const int col_base = bn * BN + wn + (lane & 15);
    const int row_base = bm * BM + ((lane >> 4) * 4);
#pragma unroll
    for (int j2 = 0; j2 < 2; ++j2) {
        int n = col_base + j2 * 16;
        if (n >= 2 * LDIM) continue;           // N-pad region: discard
        int ri = (n >= LDIM) ? 1 : 0;
        int nn = n - ri * LDIM;
        int sym = nn / NSC;
        int jj = nn - sym * NSC;
        size_t colOff = (size_t)ri * (M_DIM * ROWLEN) + sym * FFT + sc[jj];
#pragma unroll
        for (int i = 0; i < 4; ++i) {
            int row0 = row_base + i * 16;
#pragma unroll
            for (int r = 0; r < 4; ++r) {
                out[colOff + (size_t)(row0 + r) * ROWLEN] = acc[i][j2][r];
            }
        }
    }
}

// ---------------------------------------------------------------------------
extern "C" void kernel_launch(void* const* d_in, const int* in_sizes, int n_in,
                              void* d_out, int out_size, void* d_ws, size_t ws_size,
                              hipStream_t stream) {
    const float* xr = (const float*)d_in[0];
    const float* xi = (const float*)d_in[1];
    const float* Cr = (const float*)d_in[2];
    const float* Ci = (const float*)d_in[3];
    const int* sc   = (const int*)d_in[4];
    float* out = (float*)d_out;

    half_t* Ah = (half_t*)d_ws;                                      // 12.58 MB
    half_t* Wh = (half_t*)((char*)d_ws + (size_t)M_DIM * K_DIM * 2); // 18.87 MB

    prep_all<<<PREP_BLOCKS, 256, 0, stream>>>(
        xr, xi, Cr, Ci, sc, Ah, Wh, out);

    dim3 grid(N_DIM / BN, M_DIM / BM);   // (24, 32) = 768 blocks
    gemm_scatter<<<grid, 256, 0, stream>>>(Ah, Wh, sc, out);
}